// Round 5
// baseline (3632.498 us; speedup 1.0000x reference)
//
#include <hip/hip_runtime.h>
#include <math.h>

#define T_ 12
#define N_ 20000
#define E_ 320000
#define FIN_ 128
#define H_ 256
#define G_ 256
#define C_ 10

typedef __attribute__((ext_vector_type(8))) short bf16x8;
typedef __attribute__((ext_vector_type(4))) float f32x4;

// ---------------- workspace layout (bytes) ----------------
static const size_t OFF_EMB   = 0;          // T*256 f32 (zeroed each launch)
static const size_t ZERO_BYTES= 12288;
static const size_t OFF_CNT   = 12288;      // T*N i32
static const size_t OFF_DINV  = 972288;     // T*N f32
static const size_t OFF_CP    = 1932288;    // T*(N+1) i32 (padded)
static const size_t OFF_EROW  = 2892544;    // T*E i32
static const size_t OFF_ENORM = 18252544;   // T*E f32
static const size_t OFF_W1BT  = 33612544;   // 256x128 bf16
static const size_t OFF_W2BT  = 33678080;   // 256x256 bf16
static const size_t OFF_WIHT  = 33809152;   // 256x768 f32
static const size_t OFF_WHHT  = 34595584;   // 256x768 f32
static const size_t OFF_GX    = 35382016;   // 12x768 f32
static const size_t OFF_XBT   = 35418880;   // N*128 bf16
static const size_t OFF_P     = 40538880;   // N*256 bf16
static const size_t OFF_Q     = 50778880;   // N*256 bf16
// end ~61.0 MB

__device__ __forceinline__ float bf2f(unsigned short u) {
  return __uint_as_float(((unsigned int)u) << 16);
}
__device__ __forceinline__ unsigned short f2bf(float f) {
  unsigned int u = __float_as_uint(f);
  unsigned int r = (u + 0x7FFFu + ((u >> 16) & 1u)) >> 16;  // RNE
  return (unsigned short)r;
}
__device__ __forceinline__ float bflo(unsigned int u) { return __uint_as_float(u << 16); }
__device__ __forceinline__ float bfhi(unsigned int u) { return __uint_as_float(u & 0xFFFF0000u); }
__device__ __forceinline__ unsigned int packbf(float lo, float hi) {
  return (unsigned int)f2bf(lo) | ((unsigned int)f2bf(hi) << 16);
}

// ---------------- CSR build: LDS-privatized histogram (no device atomics) ----------------
__global__ __launch_bounds__(1024) void hist12(const int* __restrict__ ei,
                                               const float* __restrict__ ea,
                                               int* __restrict__ cnt,
                                               float* __restrict__ dinv) {
  __shared__ float degs[N_];            // 80 KB
  __shared__ unsigned int cntp[N_ / 2]; // 40 KB (two u16 counters per word)
  const int t = blockIdx.x;
  const int tid = threadIdx.x;
  for (int i = tid; i < N_; i += 1024) degs[i] = 0.f;
  for (int i = tid; i < N_ / 2; i += 1024) cntp[i] = 0u;
  __syncthreads();
  const int* col = ei + (size_t)t * 2 * E_ + E_;
  const float* wt = ea + (size_t)t * E_;
  for (int e = tid; e < E_; e += 1024) {
    int c = col[e];
    atomicAdd(&degs[c], wt[e]);
    atomicAdd(&cntp[c >> 1], 1u << ((c & 1) * 16));
  }
  __syncthreads();
  for (int i = tid; i < N_; i += 1024) {
    cnt[t * N_ + i] = (int)((cntp[i >> 1] >> ((i & 1) * 16)) & 0xFFFFu);
    dinv[t * N_ + i] = rsqrtf(degs[i] + 1.0f);
  }
}

__global__ __launch_bounds__(1024) void scan_kernel(const int* __restrict__ cnt,
                                                    int* __restrict__ colptr) {
  const int t = blockIdx.x;
  __shared__ int s[1024];
  const int tid = threadIdx.x;
  int base = 0;
  for (int c0 = 0; c0 < N_; c0 += 1024) {
    int i = c0 + tid;
    int v = (i < N_) ? cnt[t * N_ + i] : 0;
    s[tid] = v;
    __syncthreads();
    for (int off = 1; off < 1024; off <<= 1) {
      int add = (tid >= off) ? s[tid - off] : 0;
      __syncthreads();
      s[tid] += add;
      __syncthreads();
    }
    if (i < N_) colptr[t * (N_ + 1) + i] = base + s[tid] - v;  // exclusive
    base += s[1023];
    __syncthreads();
  }
  if (tid == 0) colptr[t * (N_ + 1) + N_] = base;
}

__global__ __launch_bounds__(1024) void fill12(const int* __restrict__ ei,
                                               const float* __restrict__ ea,
                                               const int* __restrict__ colptr,
                                               const float* __restrict__ dinv,
                                               int* __restrict__ erow,
                                               float* __restrict__ enorm) {
  __shared__ unsigned int off[N_];  // 80 KB
  const int t = blockIdx.x;
  const int tid = threadIdx.x;
  for (int i = tid; i < N_; i += 1024) off[i] = (unsigned int)colptr[t * (N_ + 1) + i];
  __syncthreads();
  const int* rowp = ei + (size_t)t * 2 * E_;
  const int* colp = rowp + E_;
  const float* wt = ea + (size_t)t * E_;
  const float* dv = dinv + (size_t)t * N_;
  int* er = erow + (size_t)t * E_;
  float* en = enorm + (size_t)t * E_;
  for (int e = tid; e < E_; e += 1024) {
    int r = rowp[e], c = colp[e];
    unsigned int pos = atomicAdd(&off[c], 1u);
    er[pos] = r;
    en[pos] = dv[r] * wt[e] * dv[c];
  }
}

// ---------------- weight prep ----------------
__global__ __launch_bounds__(256) void prep_kernel(const float* __restrict__ W1,
                                                   const float* __restrict__ W2,
                                                   const float* __restrict__ Wih,
                                                   const float* __restrict__ Whh,
                                                   unsigned short* __restrict__ W1bT,
                                                   unsigned short* __restrict__ W2bT,
                                                   float* __restrict__ WihT,
                                                   float* __restrict__ WhhT) {
  int idx = blockIdx.x * 256 + threadIdx.x;
  if (idx < 32768) {
    int n = idx >> 7, k = idx & 127;
    W1bT[idx] = f2bf(W1[k * 256 + n]);
  } else if (idx < 98304) {
    int j = idx - 32768;
    int n = j >> 8, k = j & 255;
    W2bT[j] = f2bf(W2[k * 256 + n]);
  } else if (idx < 294912) {
    int j = idx - 98304;
    int k = j / 768, c = j - k * 768;
    WihT[j] = Wih[c * 256 + k];
  } else if (idx < 491520) {
    int j = idx - 294912;
    int k = j / 768, c = j - k * 768;
    WhhT[j] = Whh[c * 256 + k];
  }
}

// ---------------- cast x_t fp32 -> bf16 ----------------
__global__ __launch_bounds__(256) void castx_kernel(const float* __restrict__ x,
                                                    unsigned short* __restrict__ xb) {
  int idx = blockIdx.x * 256 + threadIdx.x;
  float4 v = ((const float4*)x)[idx];
  ushort4 o;
  o.x = f2bf(v.x); o.y = f2bf(v.y); o.z = f2bf(v.z); o.w = f2bf(v.w);
  ((ushort4*)xb)[idx] = o;
}

// ---------------- gather aggregate (bf16 in/out, fp32 accum), incl self-loop ----------------
__global__ __launch_bounds__(256) void agg128(const unsigned short* __restrict__ h,
                                              unsigned short* __restrict__ o,
                                              const int* __restrict__ erow,
                                              const float* __restrict__ enorm,
                                              const int* __restrict__ cp,
                                              const float* __restrict__ dinv) {
  const int node = blockIdx.x * 4 + (threadIdx.x >> 6);
  const int lane = threadIdx.x & 63;
  float a0 = 0.f, a1 = 0.f;
  const int s0 = cp[node], s1 = cp[node + 1];
  for (int i = s0; i < s1; ++i) {
    const int r = erow[i];
    const float nm = enorm[i];
    unsigned int u = *(const unsigned int*)&h[(size_t)r * 128 + lane * 2];
    a0 = fmaf(nm, bflo(u), a0);
    a1 = fmaf(nm, bfhi(u), a1);
  }
  const float di = dinv[node];
  const float sw = di * di;
  unsigned int us = *(const unsigned int*)&h[(size_t)node * 128 + lane * 2];
  a0 = fmaf(sw, bflo(us), a0);
  a1 = fmaf(sw, bfhi(us), a1);
  *(unsigned int*)&o[(size_t)node * 128 + lane * 2] = packbf(a0, a1);
}

__global__ __launch_bounds__(256) void agg256(const unsigned short* __restrict__ h,
                                              unsigned short* __restrict__ o,
                                              const int* __restrict__ erow,
                                              const float* __restrict__ enorm,
                                              const int* __restrict__ cp,
                                              const float* __restrict__ dinv) {
  const int node = blockIdx.x * 4 + (threadIdx.x >> 6);
  const int lane = threadIdx.x & 63;
  float a0 = 0.f, a1 = 0.f, a2 = 0.f, a3 = 0.f;
  const int s0 = cp[node], s1 = cp[node + 1];
  for (int i = s0; i < s1; ++i) {
    const int r = erow[i];
    const float nm = enorm[i];
    uint2 u = *(const uint2*)&h[(size_t)r * 256 + lane * 4];
    a0 = fmaf(nm, bflo(u.x), a0);
    a1 = fmaf(nm, bfhi(u.x), a1);
    a2 = fmaf(nm, bflo(u.y), a2);
    a3 = fmaf(nm, bfhi(u.y), a3);
  }
  const float di = dinv[node];
  const float sw = di * di;
  uint2 us = *(const uint2*)&h[(size_t)node * 256 + lane * 4];
  a0 = fmaf(sw, bflo(us.x), a0);
  a1 = fmaf(sw, bfhi(us.x), a1);
  a2 = fmaf(sw, bflo(us.y), a2);
  a3 = fmaf(sw, bfhi(us.y), a3);
  uint2 ov;
  ov.x = packbf(a0, a1);
  ov.y = packbf(a2, a3);
  *(uint2*)&o[(size_t)node * 256 + lane * 4] = ov;
}

// ---------------- bf16 MFMA GEMM: C[M,256] = relu(A[M,K] @ BT^T + bias) ----------------
// block: 64 rows x 128 cols, 4 waves (wave w: rows (w>>1)*32, cols (w&1)*64)
template <int K>
__global__ __launch_bounds__(256) void gemm_bf16(const unsigned short* __restrict__ A,
                                                 const unsigned short* __restrict__ BT,  // [256][K]
                                                 const float* __restrict__ bias,
                                                 unsigned short* __restrict__ C, int M) {
  constexpr int LD = K + 8;  // +8 bf16 pad: rows land 4 banks apart -> 2-way (free)
  __shared__ unsigned short As[64 * LD];
  const int tid = threadIdx.x;
  const int bm = blockIdx.x * 64;
  const int bn = blockIdx.y * 128;
  {
    constexpr int CPR = K / 8;             // 16B chunks per row
    constexpr int CH = 64 * CPR / 256;     // chunks per thread
#pragma unroll
    for (int i = 0; i < CH; ++i) {
      int chunk = tid + i * 256;
      int r = chunk / CPR;
      int ck = (chunk - r * CPR) * 8;
      int row = bm + r;
      if (row >= M) row = M - 1;
      *(bf16x8*)&As[r * LD + ck] = *(const bf16x8*)&A[(size_t)row * K + ck];
    }
  }
  __syncthreads();
  const int w = tid >> 6, l = tid & 63;
  const int l16 = l & 15, lk = l >> 4;
  const int rbase = (w >> 1) * 32;
  const int colbase = bn + (w & 1) * 64;
  f32x4 acc[2][4] = {};
  for (int ks = 0; ks < K; ks += 32) {
    bf16x8 a[2], b[4];
#pragma unroll
    for (int m = 0; m < 2; ++m)
      a[m] = *(const bf16x8*)&As[(rbase + m * 16 + l16) * LD + ks + lk * 8];
#pragma unroll
    for (int n = 0; n < 4; ++n)
      b[n] = *(const bf16x8*)&BT[(size_t)(colbase + n * 16 + l16) * K + ks + lk * 8];
#pragma unroll
    for (int m = 0; m < 2; ++m)
#pragma unroll
      for (int n = 0; n < 4; ++n)
        acc[m][n] = __builtin_amdgcn_mfma_f32_16x16x32_bf16(a[m], b[n], acc[m][n], 0, 0, 0);
  }
#pragma unroll
  for (int n = 0; n < 4; ++n) {
    int col = colbase + n * 16 + l16;
    float bv = bias[col];
#pragma unroll
    for (int m = 0; m < 2; ++m) {
      int row0 = bm + rbase + m * 16 + lk * 4;
#pragma unroll
      for (int r = 0; r < 4; ++r) {
        int row = row0 + r;
        if (row < M) {
          float v = fmaxf(acc[m][n][r] + bv, 0.f);
          C[(size_t)row * 256 + col] = f2bf(v);
        }
      }
    }
  }
}

// ---------------- mean pool (bf16 in) ----------------
__global__ __launch_bounds__(256) void mean_bf16(const unsigned short* __restrict__ h,
                                                 float* __restrict__ embp) {
  const int ch = threadIdx.x;
  float acc = 0.f;
  for (int n = blockIdx.x; n < N_; n += gridDim.x)
    acc += bf2f(h[(size_t)n * 256 + ch]);
  atomicAdd(&embp[ch], acc * (1.0f / N_));
}

// ---------------- GX[t] = Wih @ emb_t + bih ----------------
__global__ __launch_bounds__(768) void gx_kernel(const float* __restrict__ emb,
                                                 const float* __restrict__ WihT,  // [256][768]
                                                 const float* __restrict__ bih,
                                                 float* __restrict__ GX) {
  const int t = blockIdx.x;
  const int tid = threadIdx.x;
  __shared__ float se[256];
  if (tid < 256) se[tid] = emb[t * 256 + tid];
  __syncthreads();
  float p0 = 0.f, p1 = 0.f, p2 = 0.f, p3 = 0.f;
#pragma unroll 8
  for (int k = 0; k < 256; k += 4) {
    p0 = fmaf(WihT[(size_t)(k + 0) * 768 + tid], se[k + 0], p0);
    p1 = fmaf(WihT[(size_t)(k + 1) * 768 + tid], se[k + 1], p1);
    p2 = fmaf(WihT[(size_t)(k + 2) * 768 + tid], se[k + 2], p2);
    p3 = fmaf(WihT[(size_t)(k + 3) * 768 + tid], se[k + 3], p3);
  }
  GX[t * 768 + tid] = (p0 + p1) + (p2 + p3) + bih[tid];
}

// ---------------- sequential GRU + final linear ----------------
__global__ __launch_bounds__(768) void gru2_kernel(const float* __restrict__ GX,
                                                   const float* __restrict__ WhhT,  // [256][768]
                                                   const float* __restrict__ bhh,
                                                   const float* __restrict__ Wc,
                                                   const float* __restrict__ bc,
                                                   float* __restrict__ out) {
  __shared__ float sh[256];
  __shared__ float sgh[768];
  const int tid = threadIdx.x;
  if (tid < 256) sh[tid] = 0.f;
  __syncthreads();
  for (int t = 0; t < T_; ++t) {
    float p0 = 0.f, p1 = 0.f, p2 = 0.f, p3 = 0.f;
#pragma unroll 8
    for (int k = 0; k < 256; k += 4) {
      p0 = fmaf(WhhT[(size_t)(k + 0) * 768 + tid], sh[k + 0], p0);
      p1 = fmaf(WhhT[(size_t)(k + 1) * 768 + tid], sh[k + 1], p1);
      p2 = fmaf(WhhT[(size_t)(k + 2) * 768 + tid], sh[k + 2], p2);
      p3 = fmaf(WhhT[(size_t)(k + 3) * 768 + tid], sh[k + 3], p3);
    }
    sgh[tid] = (p0 + p1) + (p2 + p3) + bhh[tid];
    __syncthreads();
    if (tid < 256) {
      const float* gx = &GX[t * 768];
      float r = 1.f / (1.f + __expf(-(gx[tid] + sgh[tid])));
      float z = 1.f / (1.f + __expf(-(gx[256 + tid] + sgh[256 + tid])));
      float n = tanhf(gx[512 + tid] + r * sgh[512 + tid]);
      sh[tid] = (1.f - z) * n + z * sh[tid];
    }
    __syncthreads();
  }
  const int wv = tid >> 6, lane = tid & 63;
  if (wv < C_) {
    float p = 0.f;
#pragma unroll
    for (int i = 0; i < 4; ++i) {
      int j = lane + 64 * i;
      p += sh[j] * Wc[(size_t)j * C_ + wv];
    }
    for (int off = 32; off > 0; off >>= 1) p += __shfl_down(p, off);
    if (lane == 0) out[wv] = p + bc[wv];
  }
}

extern "C" void kernel_launch(void* const* d_in, const int* in_sizes, int n_in,
                              void* d_out, int out_size, void* d_ws, size_t ws_size,
                              hipStream_t stream) {
  const float* x   = (const float*)d_in[0];
  const int*   ei  = (const int*)d_in[1];
  const float* ea  = (const float*)d_in[2];
  const float* W1  = (const float*)d_in[3];
  const float* b1  = (const float*)d_in[4];
  const float* W2  = (const float*)d_in[5];
  const float* b2  = (const float*)d_in[6];
  const float* Wih = (const float*)d_in[7];
  const float* Whh = (const float*)d_in[8];
  const float* bih = (const float*)d_in[9];
  const float* bhh = (const float*)d_in[10];
  const float* Wc  = (const float*)d_in[11];
  const float* bc  = (const float*)d_in[12];
  float* out = (float*)d_out;

  char* w = (char*)d_ws;
  float* emb   = (float*)(w + OFF_EMB);
  int*   cnt   = (int*)(w + OFF_CNT);
  float* dinv  = (float*)(w + OFF_DINV);
  int*   cp    = (int*)(w + OFF_CP);
  int*   erow  = (int*)(w + OFF_EROW);
  float* enorm = (float*)(w + OFF_ENORM);
  unsigned short* W1bT = (unsigned short*)(w + OFF_W1BT);
  unsigned short* W2bT = (unsigned short*)(w + OFF_W2BT);
  float* WihT  = (float*)(w + OFF_WIHT);
  float* WhhT  = (float*)(w + OFF_WHHT);
  float* GX    = (float*)(w + OFF_GX);
  unsigned short* xbt = (unsigned short*)(w + OFF_XBT);
  unsigned short* P   = (unsigned short*)(w + OFF_P);
  unsigned short* Q   = (unsigned short*)(w + OFF_Q);

  hipMemsetAsync(d_ws, 0, ZERO_BYTES, stream);

  prep_kernel<<<1920, 256, 0, stream>>>(W1, W2, Wih, Whh, W1bT, W2bT, WihT, WhhT);

  hist12<<<T_, 1024, 0, stream>>>(ei, ea, cnt, dinv);
  scan_kernel<<<T_, 1024, 0, stream>>>(cnt, cp);
  fill12<<<T_, 1024, 0, stream>>>(ei, ea, cp, dinv, erow, enorm);

  dim3 gemm_grid((N_ + 63) / 64, 2);
  for (int t = 0; t < T_; ++t) {
    const int* cpt = cp + (size_t)t * (N_ + 1);
    const int* ert = erow + (size_t)t * E_;
    const float* ent = enorm + (size_t)t * E_;
    const float* dvt = dinv + (size_t)t * N_;
    castx_kernel<<<2500, 256, 0, stream>>>(x + (size_t)t * N_ * FIN_, xbt);
    agg128<<<N_ / 4, 256, 0, stream>>>(xbt, P, ert, ent, cpt, dvt);
    gemm_bf16<FIN_><<<gemm_grid, 256, 0, stream>>>(P, W1bT, b1, Q, N_);
    agg256<<<N_ / 4, 256, 0, stream>>>(Q, P, ert, ent, cpt, dvt);
    gemm_bf16<H_><<<gemm_grid, 256, 0, stream>>>(P, W2bT, b2, Q, N_);
    mean_bf16<<<128, 256, 0, stream>>>(Q, emb + t * H_);
  }
  gx_kernel<<<T_, 768, 0, stream>>>(emb, WihT, bih, GX);
  gru2_kernel<<<1, 768, 0, stream>>>(GX, WhhT, bhh, Wc, bc, out);
}

// Round 6
// 2299.270 us; speedup vs baseline: 1.5798x; 1.5798x over previous
//
#include <hip/hip_runtime.h>
#include <math.h>

#define T_ 12
#define N_ 20000
#define E_ 320000
#define FIN_ 128
#define H_ 256
#define G_ 256
#define C_ 10
#define ECH 8
#define EPC (E_ / ECH)  // 40000 edges per chunk

typedef __attribute__((ext_vector_type(8))) short bf16x8;
typedef __attribute__((ext_vector_type(4))) float f32x4;

// ---------------- workspace layout (bytes) ----------------
static const size_t OFF_EMB   = 0;          // T*256 f32 (zeroed each launch)
static const size_t ZERO_BYTES= 12288;
static const size_t OFF_DINV  = 12288;      // T*N f32
static const size_t OFF_CP    = 972288;     // T*(N+1) i32 (padded to 960256)
static const size_t OFF_DEGP  = 1932544;    // T*ECH*N f32 partial degrees
static const size_t OFF_CNT16 = 9612544;    // T*ECH*N u16 partial counts
static const size_t OFF_CUM   = 13452544;   // T*ECH*N u32 per-chunk slot bases
static const size_t OFF_EROW  = 21132544;   // T*E i32
static const size_t OFF_ENORM = 36492544;   // T*E f32
static const size_t OFF_W1BT  = 51852544;   // 256x128 bf16
static const size_t OFF_W2BT  = 51918080;   // 256x256 bf16
static const size_t OFF_WIHT  = 52049152;   // 256x768 f32
static const size_t OFF_WHHT  = 52835584;   // 256x768 f32
static const size_t OFF_GX    = 53622016;   // 12x768 f32
static const size_t OFF_XBT   = 53658880;   // N*128 bf16
static const size_t OFF_P     = 58778880;   // N*256 bf16
static const size_t OFF_Q     = 69018880;   // N*256 bf16
// end ~79.3 MB

__device__ __forceinline__ float bf2f(unsigned short u) {
  return __uint_as_float(((unsigned int)u) << 16);
}
__device__ __forceinline__ unsigned short f2bf(float f) {
  unsigned int u = __float_as_uint(f);
  unsigned int r = (u + 0x7FFFu + ((u >> 16) & 1u)) >> 16;  // RNE
  return (unsigned short)r;
}
__device__ __forceinline__ float bflo(unsigned int u) { return __uint_as_float(u << 16); }
__device__ __forceinline__ float bfhi(unsigned int u) { return __uint_as_float(u & 0xFFFF0000u); }
__device__ __forceinline__ unsigned int packbf(float lo, float hi) {
  return (unsigned int)f2bf(lo) | ((unsigned int)f2bf(hi) << 16);
}

// ---------------- partial histogram: block (t, ech) owns edges [ech*EPC, +EPC) ----------------
__global__ __launch_bounds__(1024) void histp(const int* __restrict__ ei,
                                              const float* __restrict__ ea,
                                              float* __restrict__ degp,
                                              unsigned short* __restrict__ cnt16) {
  __shared__ float degs[N_];            // 80 KB
  __shared__ unsigned int cntp[N_ / 2]; // 40 KB (two u16 counters per word)
  const int t = blockIdx.x, ech = blockIdx.y;
  const int tid = threadIdx.x;
  for (int i = tid; i < N_; i += 1024) degs[i] = 0.f;
  for (int i = tid; i < N_ / 2; i += 1024) cntp[i] = 0u;
  __syncthreads();
  const int* col = ei + (size_t)t * 2 * E_ + E_ + ech * EPC;
  const float* wt = ea + (size_t)t * E_ + ech * EPC;
  for (int e = tid; e < EPC; e += 1024) {
    int c = col[e];
    atomicAdd(&degs[c], wt[e]);
    atomicAdd(&cntp[c >> 1], 1u << ((c & 1) * 16));
  }
  __syncthreads();
  float* dp = degp + ((size_t)t * ECH + ech) * N_;
  unsigned short* cp16 = cnt16 + ((size_t)t * ECH + ech) * N_;
  for (int i = tid; i < N_; i += 1024) {
    dp[i] = degs[i];
    cp16[i] = (unsigned short)((cntp[i >> 1] >> ((i & 1) * 16)) & 0xFFFFu);
  }
}

// ---------------- reduce partials + scan + per-chunk cumulative bases + dinv ----------------
__global__ __launch_bounds__(1024) void scan2(const float* __restrict__ degp,
                                              const unsigned short* __restrict__ cnt16,
                                              int* __restrict__ colptr,
                                              unsigned int* __restrict__ cum,
                                              float* __restrict__ dinv) {
  const int t = blockIdx.x;
  __shared__ int s[1024];
  const int tid = threadIdx.x;
  int base = 0;
  for (int c0 = 0; c0 < N_; c0 += 1024) {
    int n = c0 + tid;
    int cc[ECH];
    int tot = 0;
    float dg = 0.f;
    if (n < N_) {
#pragma unroll
      for (int ch = 0; ch < ECH; ++ch) {
        cc[ch] = cnt16[((size_t)t * ECH + ch) * N_ + n];
        tot += cc[ch];
        dg += degp[((size_t)t * ECH + ch) * N_ + n];
      }
    }
    s[tid] = tot;
    __syncthreads();
    for (int off = 1; off < 1024; off <<= 1) {
      int add = (tid >= off) ? s[tid - off] : 0;
      __syncthreads();
      s[tid] += add;
      __syncthreads();
    }
    if (n < N_) {
      int start = base + s[tid] - tot;
      colptr[t * (N_ + 1) + n] = start;
      unsigned int run = (unsigned int)start;
#pragma unroll
      for (int ch = 0; ch < ECH; ++ch) {
        cum[((size_t)t * ECH + ch) * N_ + n] = run;
        run += (unsigned int)cc[ch];
      }
      dinv[t * N_ + n] = rsqrtf(dg + 1.0f);
    }
    base += s[1023];
    __syncthreads();
  }
  if (tid == 0) colptr[t * (N_ + 1) + N_] = base;
}

// ---------------- CSR fill: block (t, ech) has exclusive slot ranges via cum ----------------
__global__ __launch_bounds__(1024) void fillE(const int* __restrict__ ei,
                                              const float* __restrict__ ea,
                                              const unsigned int* __restrict__ cum,
                                              const float* __restrict__ dinv,
                                              int* __restrict__ erow,
                                              float* __restrict__ enorm) {
  __shared__ unsigned int off[N_];  // 80 KB
  const int t = blockIdx.x, ech = blockIdx.y;
  const int tid = threadIdx.x;
  const unsigned int* cm = cum + ((size_t)t * ECH + ech) * N_;
  for (int i = tid; i < N_; i += 1024) off[i] = cm[i];
  __syncthreads();
  const int* rowp = ei + (size_t)t * 2 * E_ + ech * EPC;
  const int* colp = rowp + E_;
  const float* wt = ea + (size_t)t * E_ + ech * EPC;
  const float* dv = dinv + (size_t)t * N_;
  int* er = erow + (size_t)t * E_;
  float* en = enorm + (size_t)t * E_;
  for (int e = tid; e < EPC; e += 1024) {
    int r = rowp[e], c = colp[e];
    unsigned int pos = atomicAdd(&off[c], 1u);
    er[pos] = r;
    en[pos] = dv[r] * wt[e] * dv[c];
  }
}

// ---------------- weight prep ----------------
__global__ __launch_bounds__(256) void prep_kernel(const float* __restrict__ W1,
                                                   const float* __restrict__ W2,
                                                   const float* __restrict__ Wih,
                                                   const float* __restrict__ Whh,
                                                   unsigned short* __restrict__ W1bT,
                                                   unsigned short* __restrict__ W2bT,
                                                   float* __restrict__ WihT,
                                                   float* __restrict__ WhhT) {
  int idx = blockIdx.x * 256 + threadIdx.x;
  if (idx < 32768) {
    int n = idx >> 7, k = idx & 127;
    W1bT[idx] = f2bf(W1[k * 256 + n]);
  } else if (idx < 98304) {
    int j = idx - 32768;
    int n = j >> 8, k = j & 255;
    W2bT[j] = f2bf(W2[k * 256 + n]);
  } else if (idx < 294912) {
    int j = idx - 98304;
    int k = j / 768, c = j - k * 768;
    WihT[j] = Wih[c * 256 + k];
  } else if (idx < 491520) {
    int j = idx - 294912;
    int k = j / 768, c = j - k * 768;
    WhhT[j] = Whh[c * 256 + k];
  }
}

// ---------------- cast x_t fp32 -> bf16 ----------------
__global__ __launch_bounds__(256) void castx_kernel(const float* __restrict__ x,
                                                    unsigned short* __restrict__ xb) {
  int idx = blockIdx.x * 256 + threadIdx.x;
  float4 v = ((const float4*)x)[idx];
  ushort4 o;
  o.x = f2bf(v.x); o.y = f2bf(v.y); o.z = f2bf(v.z); o.w = f2bf(v.w);
  ((ushort4*)xb)[idx] = o;
}

// ---------------- gather aggregate (bf16 in/out, fp32 accum), incl self-loop ----------------
__global__ __launch_bounds__(256) void agg128(const unsigned short* __restrict__ h,
                                              unsigned short* __restrict__ o,
                                              const int* __restrict__ erow,
                                              const float* __restrict__ enorm,
                                              const int* __restrict__ cp,
                                              const float* __restrict__ dinv) {
  const int node = blockIdx.x * 4 + (threadIdx.x >> 6);
  const int lane = threadIdx.x & 63;
  float a0 = 0.f, a1 = 0.f;
  const int s0 = cp[node], s1 = cp[node + 1];
  for (int i = s0; i < s1; ++i) {
    const int r = erow[i];
    const float nm = enorm[i];
    unsigned int u = *(const unsigned int*)&h[(size_t)r * 128 + lane * 2];
    a0 = fmaf(nm, bflo(u), a0);
    a1 = fmaf(nm, bfhi(u), a1);
  }
  const float di = dinv[node];
  const float sw = di * di;
  unsigned int us = *(const unsigned int*)&h[(size_t)node * 128 + lane * 2];
  a0 = fmaf(sw, bflo(us), a0);
  a1 = fmaf(sw, bfhi(us), a1);
  *(unsigned int*)&o[(size_t)node * 128 + lane * 2] = packbf(a0, a1);
}

__global__ __launch_bounds__(256) void agg256(const unsigned short* __restrict__ h,
                                              unsigned short* __restrict__ o,
                                              const int* __restrict__ erow,
                                              const float* __restrict__ enorm,
                                              const int* __restrict__ cp,
                                              const float* __restrict__ dinv) {
  const int node = blockIdx.x * 4 + (threadIdx.x >> 6);
  const int lane = threadIdx.x & 63;
  float a0 = 0.f, a1 = 0.f, a2 = 0.f, a3 = 0.f;
  const int s0 = cp[node], s1 = cp[node + 1];
  for (int i = s0; i < s1; ++i) {
    const int r = erow[i];
    const float nm = enorm[i];
    uint2 u = *(const uint2*)&h[(size_t)r * 256 + lane * 4];
    a0 = fmaf(nm, bflo(u.x), a0);
    a1 = fmaf(nm, bfhi(u.x), a1);
    a2 = fmaf(nm, bflo(u.y), a2);
    a3 = fmaf(nm, bfhi(u.y), a3);
  }
  const float di = dinv[node];
  const float sw = di * di;
  uint2 us = *(const uint2*)&h[(size_t)node * 256 + lane * 4];
  a0 = fmaf(sw, bflo(us.x), a0);
  a1 = fmaf(sw, bfhi(us.x), a1);
  a2 = fmaf(sw, bflo(us.y), a2);
  a3 = fmaf(sw, bfhi(us.y), a3);
  uint2 ov;
  ov.x = packbf(a0, a1);
  ov.y = packbf(a2, a3);
  *(uint2*)&o[(size_t)node * 256 + lane * 4] = ov;
}

// ---------------- bf16 MFMA GEMM: C[M,256] = relu(A[M,K] @ BT^T + bias) ----------------
// block: 64 rows x 128 cols, 4 waves (wave w: rows (w>>1)*32, cols (w&1)*64)
template <int K>
__global__ __launch_bounds__(256) void gemm_bf16(const unsigned short* __restrict__ A,
                                                 const unsigned short* __restrict__ BT,  // [256][K]
                                                 const float* __restrict__ bias,
                                                 unsigned short* __restrict__ C, int M) {
  constexpr int LD = K + 8;  // +8 bf16 pad: rows land 4 banks apart -> 2-way (free)
  __shared__ unsigned short As[64 * LD];
  const int tid = threadIdx.x;
  const int bm = blockIdx.x * 64;
  const int bn = blockIdx.y * 128;
  {
    constexpr int CPR = K / 8;             // 16B chunks per row
    constexpr int CH = 64 * CPR / 256;     // chunks per thread
#pragma unroll
    for (int i = 0; i < CH; ++i) {
      int chunk = tid + i * 256;
      int r = chunk / CPR;
      int ck = (chunk - r * CPR) * 8;
      int row = bm + r;
      if (row >= M) row = M - 1;
      *(bf16x8*)&As[r * LD + ck] = *(const bf16x8*)&A[(size_t)row * K + ck];
    }
  }
  __syncthreads();
  const int w = tid >> 6, l = tid & 63;
  const int l16 = l & 15, lk = l >> 4;
  const int rbase = (w >> 1) * 32;
  const int colbase = bn + (w & 1) * 64;
  f32x4 acc[2][4] = {};
  for (int ks = 0; ks < K; ks += 32) {
    bf16x8 a[2], b[4];
#pragma unroll
    for (int m = 0; m < 2; ++m)
      a[m] = *(const bf16x8*)&As[(rbase + m * 16 + l16) * LD + ks + lk * 8];
#pragma unroll
    for (int n = 0; n < 4; ++n)
      b[n] = *(const bf16x8*)&BT[(size_t)(colbase + n * 16 + l16) * K + ks + lk * 8];
#pragma unroll
    for (int m = 0; m < 2; ++m)
#pragma unroll
      for (int n = 0; n < 4; ++n)
        acc[m][n] = __builtin_amdgcn_mfma_f32_16x16x32_bf16(a[m], b[n], acc[m][n], 0, 0, 0);
  }
#pragma unroll
  for (int n = 0; n < 4; ++n) {
    int col = colbase + n * 16 + l16;
    float bv = bias[col];
#pragma unroll
    for (int m = 0; m < 2; ++m) {
      int row0 = bm + rbase + m * 16 + lk * 4;
#pragma unroll
      for (int r = 0; r < 4; ++r) {
        int row = row0 + r;
        if (row < M) {
          float v = fmaxf(acc[m][n][r] + bv, 0.f);
          C[(size_t)row * 256 + col] = f2bf(v);
        }
      }
    }
  }
}

// ---------------- mean pool (bf16 in) ----------------
__global__ __launch_bounds__(256) void mean_bf16(const unsigned short* __restrict__ h,
                                                 float* __restrict__ embp) {
  const int ch = threadIdx.x;
  float acc = 0.f;
  for (int n = blockIdx.x; n < N_; n += gridDim.x)
    acc += bf2f(h[(size_t)n * 256 + ch]);
  atomicAdd(&embp[ch], acc * (1.0f / N_));
}

// ---------------- GX[t] = Wih @ emb_t + bih ----------------
__global__ __launch_bounds__(768) void gx_kernel(const float* __restrict__ emb,
                                                 const float* __restrict__ WihT,  // [256][768]
                                                 const float* __restrict__ bih,
                                                 float* __restrict__ GX) {
  const int t = blockIdx.x;
  const int tid = threadIdx.x;
  __shared__ float se[256];
  if (tid < 256) se[tid] = emb[t * 256 + tid];
  __syncthreads();
  float p0 = 0.f, p1 = 0.f, p2 = 0.f, p3 = 0.f;
#pragma unroll 8
  for (int k = 0; k < 256; k += 4) {
    p0 = fmaf(WihT[(size_t)(k + 0) * 768 + tid], se[k + 0], p0);
    p1 = fmaf(WihT[(size_t)(k + 1) * 768 + tid], se[k + 1], p1);
    p2 = fmaf(WihT[(size_t)(k + 2) * 768 + tid], se[k + 2], p2);
    p3 = fmaf(WihT[(size_t)(k + 3) * 768 + tid], se[k + 3], p3);
  }
  GX[t * 768 + tid] = (p0 + p1) + (p2 + p3) + bih[tid];
}

// ---------------- sequential GRU + final linear ----------------
__global__ __launch_bounds__(768) void gru2_kernel(const float* __restrict__ GX,
                                                   const float* __restrict__ WhhT,  // [256][768]
                                                   const float* __restrict__ bhh,
                                                   const float* __restrict__ Wc,
                                                   const float* __restrict__ bc,
                                                   float* __restrict__ out) {
  __shared__ float sh[256];
  __shared__ float sgh[768];
  const int tid = threadIdx.x;
  if (tid < 256) sh[tid] = 0.f;
  __syncthreads();
  for (int t = 0; t < T_; ++t) {
    float p0 = 0.f, p1 = 0.f, p2 = 0.f, p3 = 0.f;
#pragma unroll 8
    for (int k = 0; k < 256; k += 4) {
      p0 = fmaf(WhhT[(size_t)(k + 0) * 768 + tid], sh[k + 0], p0);
      p1 = fmaf(WhhT[(size_t)(k + 1) * 768 + tid], sh[k + 1], p1);
      p2 = fmaf(WhhT[(size_t)(k + 2) * 768 + tid], sh[k + 2], p2);
      p3 = fmaf(WhhT[(size_t)(k + 3) * 768 + tid], sh[k + 3], p3);
    }
    sgh[tid] = (p0 + p1) + (p2 + p3) + bhh[tid];
    __syncthreads();
    if (tid < 256) {
      const float* gx = &GX[t * 768];
      float r = 1.f / (1.f + __expf(-(gx[tid] + sgh[tid])));
      float z = 1.f / (1.f + __expf(-(gx[256 + tid] + sgh[256 + tid])));
      float n = tanhf(gx[512 + tid] + r * sgh[512 + tid]);
      sh[tid] = (1.f - z) * n + z * sh[tid];
    }
    __syncthreads();
  }
  const int wv = tid >> 6, lane = tid & 63;
  if (wv < C_) {
    float p = 0.f;
#pragma unroll
    for (int i = 0; i < 4; ++i) {
      int j = lane + 64 * i;
      p += sh[j] * Wc[(size_t)j * C_ + wv];
    }
    for (int off = 32; off > 0; off >>= 1) p += __shfl_down(p, off);
    if (lane == 0) out[wv] = p + bc[wv];
  }
}

extern "C" void kernel_launch(void* const* d_in, const int* in_sizes, int n_in,
                              void* d_out, int out_size, void* d_ws, size_t ws_size,
                              hipStream_t stream) {
  const float* x   = (const float*)d_in[0];
  const int*   ei  = (const int*)d_in[1];
  const float* ea  = (const float*)d_in[2];
  const float* W1  = (const float*)d_in[3];
  const float* b1  = (const float*)d_in[4];
  const float* W2  = (const float*)d_in[5];
  const float* b2  = (const float*)d_in[6];
  const float* Wih = (const float*)d_in[7];
  const float* Whh = (const float*)d_in[8];
  const float* bih = (const float*)d_in[9];
  const float* bhh = (const float*)d_in[10];
  const float* Wc  = (const float*)d_in[11];
  const float* bc  = (const float*)d_in[12];
  float* out = (float*)d_out;

  char* w = (char*)d_ws;
  float* emb   = (float*)(w + OFF_EMB);
  float* dinv  = (float*)(w + OFF_DINV);
  int*   cp    = (int*)(w + OFF_CP);
  float* degp  = (float*)(w + OFF_DEGP);
  unsigned short* cnt16 = (unsigned short*)(w + OFF_CNT16);
  unsigned int* cum = (unsigned int*)(w + OFF_CUM);
  int*   erow  = (int*)(w + OFF_EROW);
  float* enorm = (float*)(w + OFF_ENORM);
  unsigned short* W1bT = (unsigned short*)(w + OFF_W1BT);
  unsigned short* W2bT = (unsigned short*)(w + OFF_W2BT);
  float* WihT  = (float*)(w + OFF_WIHT);
  float* WhhT  = (float*)(w + OFF_WHHT);
  float* GX    = (float*)(w + OFF_GX);
  unsigned short* xbt = (unsigned short*)(w + OFF_XBT);
  unsigned short* P   = (unsigned short*)(w + OFF_P);
  unsigned short* Q   = (unsigned short*)(w + OFF_Q);

  hipMemsetAsync(d_ws, 0, ZERO_BYTES, stream);

  prep_kernel<<<1920, 256, 0, stream>>>(W1, W2, Wih, Whh, W1bT, W2bT, WihT, WhhT);

  dim3 csr_grid(T_, ECH);
  histp<<<csr_grid, 1024, 0, stream>>>(ei, ea, degp, cnt16);
  scan2<<<T_, 1024, 0, stream>>>(degp, cnt16, cp, cum, dinv);
  fillE<<<csr_grid, 1024, 0, stream>>>(ei, ea, cum, dinv, erow, enorm);

  dim3 gemm_grid((N_ + 63) / 64, 2);
  for (int t = 0; t < T_; ++t) {
    const int* cpt = cp + (size_t)t * (N_ + 1);
    const int* ert = erow + (size_t)t * E_;
    const float* ent = enorm + (size_t)t * E_;
    const float* dvt = dinv + (size_t)t * N_;
    castx_kernel<<<2500, 256, 0, stream>>>(x + (size_t)t * N_ * FIN_, xbt);
    agg128<<<N_ / 4, 256, 0, stream>>>(xbt, P, ert, ent, cpt, dvt);
    gemm_bf16<FIN_><<<gemm_grid, 256, 0, stream>>>(P, W1bT, b1, Q, N_);
    agg256<<<N_ / 4, 256, 0, stream>>>(Q, P, ert, ent, cpt, dvt);
    gemm_bf16<H_><<<gemm_grid, 256, 0, stream>>>(P, W2bT, b2, Q, N_);
    mean_bf16<<<128, 256, 0, stream>>>(Q, emb + t * H_);
  }
  gx_kernel<<<T_, 768, 0, stream>>>(emb, WihT, bih, GX);
  gru2_kernel<<<1, 768, 0, stream>>>(GX, WhhT, bhh, Wc, bc, out);
}